// Round 7
// baseline (201.378 us; speedup 1.0000x reference)
//
#include <hip/hip_runtime.h>

#define D_DIM 1024
#define NROWS 8192

typedef float f32x4 __attribute__((ext_vector_type(4)));
typedef int   i32x4 __attribute__((ext_vector_type(4)));
typedef int   i32x8 __attribute__((ext_vector_type(8)));

typedef const __attribute__((address_space(1))) void* gaddr_t;
typedef __attribute__((address_space(3))) void* laddr_t;

__device__ __forceinline__ void load16_to_lds(const void* g, void* l) {
    __builtin_amdgcn_global_load_lds((gaddr_t)g, (laddr_t)l, 16, 0, 0);
}

// ---- kernel 1: fp32 row-normalize -> fp8 e4m3, one WAVE per row (no barriers).
// K is PERMUTED within each 128-element block (identically for A and B — dot
// products are K-permutation-invariant): orig k = 32s+8f+b (s=step 0..3,
// f=lane quarter 0..3, b=0..7) stored at byte (f + 4*(s>>1))*16 + (s&1)*8 + b.
// R17 restructure: lane l owns dest 16-B chunk at byte 16*l. Inverting the
// permutation, chunk l = {blk=l>>3, q=(l>>2)&1, f=l&3} holds orig elements
// [base,base+8) and [base+32,base+40) with base = 128*blk + 64*q + 8*f:
//   word0=pack(base+0..3) word1=pack(base+4..7)   (s=2q,  s&1=0, bytes 0-7)
//   word2=pack(base+32..35) word3=pack(base+36..39) (s=2q+1, s&1=1, bytes 8-15)
// -> ONE fully-coalesced 16-B store/lane (1 KB/wave) replaces 4 scattered
// dword stores; 4 coalesced float4 loads/lane cover the row exactly once.
// Layout bytes are bit-identical to the previous version (gemm contract kept).
// Also zeroes the encoded-max array and d_out (poisoned 0xAA every launch).
__global__ __launch_bounds__(256) void normalize_rows(const float* __restrict__ ex,
                                                      const float* __restrict__ ey,
                                                      unsigned char* __restrict__ Aq,
                                                      unsigned char* __restrict__ Bq,
                                                      int* __restrict__ maxenc,
                                                      float* __restrict__ out) {
    const int wave = threadIdx.x >> 6, lane = threadIdx.x & 63;
    const int r = blockIdx.x * 4 + wave;
    if (lane == 0) maxenc[r] = 0;   // 0 < int-encoding of any (cosine+2.0) > 0
    if (blockIdx.x == 0 && threadIdx.x < 2) out[threadIdx.x] = 0.0f;

    const float* src;
    unsigned char* dst;
    if (r < NROWS) { src = ex + (size_t)r * D_DIM;           dst = Aq + (size_t)r * D_DIM; }
    else           { src = ey + (size_t)(r - NROWS) * D_DIM; dst = Bq + (size_t)(r - NROWS) * D_DIM; }

    const int base4 = (lane >> 3) * 32 + ((lane >> 2) & 1) * 16 + (lane & 3) * 2; // float4 idx of base
    float4 va = ((const float4*)src)[base4];       // elements base .. base+3
    float4 vb = ((const float4*)src)[base4 + 1];   // base+4 .. base+7
    float4 vc = ((const float4*)src)[base4 + 8];   // base+32 .. base+35
    float4 vd = ((const float4*)src)[base4 + 9];   // base+36 .. base+39

    float ss = va.x * va.x + va.y * va.y + va.z * va.z + va.w * va.w
             + vb.x * vb.x + vb.y * vb.y + vb.z * vb.z + vb.w * vb.w
             + vc.x * vc.x + vc.y * vc.y + vc.z * vc.z + vc.w * vc.w
             + vd.x * vd.x + vd.y * vd.y + vd.z * vd.z + vd.w * vd.w;
    #pragma unroll
    for (int off = 32; off; off >>= 1) ss += __shfl_xor(ss, off, 64);
    float sc = 1.0f / fmaxf(sqrtf(ss), 1e-8f);

    i32x4 o;   // v_cvt_pk_fp8_f32: RNE, saturating; |x| <= ~0.3, no overflow
    int w;
    w = __builtin_amdgcn_cvt_pk_fp8_f32(va.x * sc, va.y * sc, 0, false);
    o[0] = __builtin_amdgcn_cvt_pk_fp8_f32(va.z * sc, va.w * sc, w, true);
    w = __builtin_amdgcn_cvt_pk_fp8_f32(vb.x * sc, vb.y * sc, 0, false);
    o[1] = __builtin_amdgcn_cvt_pk_fp8_f32(vb.z * sc, vb.w * sc, w, true);
    w = __builtin_amdgcn_cvt_pk_fp8_f32(vc.x * sc, vc.y * sc, 0, false);
    o[2] = __builtin_amdgcn_cvt_pk_fp8_f32(vc.z * sc, vc.w * sc, w, true);
    w = __builtin_amdgcn_cvt_pk_fp8_f32(vd.x * sc, vd.y * sc, 0, false);
    o[3] = __builtin_amdgcn_cvt_pk_fp8_f32(vd.z * sc, vd.w * sc, w, true);
    ((i32x4*)dst)[lane] = o;
}

// ---- kernel 2: 128x128-tile fp8 MFMA GEMM (C = A . B^T) with fused row/col max.
// Frame: BK=128, 32 KB x 2 double-buffered LDS, zero bank conflicts (16-B XOR
// swizzle + K-permutation), XCD-aware 8x8 supertile block swizzle. MX-scaled
// v_mfma_scale_f32_16x16x128_f8f6f4 with unit scales (E8M0 0x7F = 2^0) =
// numerically identical fp8 math at ~2x the non-scaled rate (~4.66 PF).
// Register history: any kt-unroll balloons addressing (R13: 244 VGPR) and
// spills under caps (R11/12/15); #pragma unroll 1 + incremental pointers
// keeps demand ~64 arch + 64 acc (R16: 86 us, MfmaUtil 33%, no spill).
// R17: T3 minimum 2-phase double-buffer. R16's single-buffer loop serialized
// stage->vmcnt(0)->compute (~900 cyc HBM drain in every iteration's critical
// path). Now tile t+1's global_load_lds are issued BEFORE tile t's compute and
// drain at the end-of-iter __syncthreads (residual wait ~= load_lat - compute
// ~= 0). The two barriers/iter merge into ONE: the end barrier both protects
// buf[(t+1)&1] (last read in iter t-1) and publishes the prefetched tile.
// Cost: 64 KB LDS -> 2 blocks/CU; win: stage latency off the serial path.
__global__ __launch_bounds__(256, 2) void gemm_max(const unsigned char* __restrict__ A,
                                                   const unsigned char* __restrict__ B,
                                                   int* __restrict__ rowmax,
                                                   int* __restrict__ colmax) {
    __shared__ __align__(16) unsigned char Alds[2][128 * 128];   // 32 KB
    __shared__ __align__(16) unsigned char Blds[2][128 * 128];   // 32 KB

    const int bid = blockIdx.x;
    const int sgr = bid >> 6;
    const int bm  = ((sgr & 7) << 3) | ((bid >> 3) & 7);
    const int bn  = ((sgr >> 3) << 3) | (bid & 7);
    const int rowb = bm * 128;
    const int colb = bn * 128;

    const int t    = threadIdx.x;
    const int lane = t & 63;
    const int wave = t >> 6;
    const int wm = (wave & 1) * 64;       // wave row offset within tile
    const int wn = (wave >> 1) * 64;      // wave col offset within tile
    const int fr = lane & 15;             // fragment row/col index
    const int fq = lane >> 4;             // quarter: k-chunk index
    const int pos1 = (fq ^ (fr & 7)) * 16;   // swizzled LDS pos of chunk fq

    // staging: thread t stages LDS (row t>>3, pos t&7) <- global chunk (t&7)^(row&7)
    const int srow = t >> 3;
    const int scol = ((t ^ (t >> 3)) & 7) * 16;

    const unsigned char* ag = A + (size_t)(rowb + srow) * D_DIM + scol;
    const unsigned char* bg = B + (size_t)(colb + srow) * D_DIM + scol;

    f32x4 acc[4][4] = {};

    // prologue: stage tile 0 into buffer 0
    #pragma unroll
    for (int i = 0; i < 4; ++i)
        load16_to_lds(ag + (size_t)i * 32 * D_DIM,
                      (char*)Alds[0] + i * 4096 + wave * 1024);
    #pragma unroll
    for (int i = 0; i < 4; ++i)
        load16_to_lds(bg + (size_t)i * 32 * D_DIM,
                      (char*)Blds[0] + i * 4096 + wave * 1024);
    ag += 128;
    bg += 128;
    __syncthreads();   // drains vmcnt -> tile 0 visible

    #pragma unroll 1
    for (int tt = 0; tt < 8; ++tt) {
        const unsigned char* Ac = Alds[tt & 1];
        const unsigned char* Bc = Blds[tt & 1];

        if (tt < 7) {   // uniform branch: prefetch tile tt+1 into the other buffer
            char* An = (char*)Alds[(tt + 1) & 1];
            char* Bn = (char*)Blds[(tt + 1) & 1];
            #pragma unroll
            for (int i = 0; i < 4; ++i)
                load16_to_lds(ag + (size_t)i * 32 * D_DIM, An + i * 4096 + wave * 1024);
            #pragma unroll
            for (int i = 0; i < 4; ++i)
                load16_to_lds(bg + (size_t)i * 32 * D_DIM, Bn + i * 4096 + wave * 1024);
            ag += 128;
            bg += 128;
        }

        // A fragments: 4 rows x 32 B (chunk fq then chunk fq^4, same order as B)
        i32x8 af[4];
        #pragma unroll
        for (int i = 0; i < 4; ++i) {
            i32x4 lo = *(const i32x4*)(Ac + (wm + i * 16 + fr) * 128 + pos1);
            i32x4 hi = *(const i32x4*)(Ac + (wm + i * 16 + fr) * 128 + (pos1 ^ 64));
            af[i] = __builtin_shufflevector(lo, hi, 0, 1, 2, 3, 4, 5, 6, 7);
        }
        #pragma unroll
        for (int j = 0; j < 4; ++j) {
            i32x4 lo = *(const i32x4*)(Bc + (wn + j * 16 + fr) * 128 + pos1);
            i32x4 hi = *(const i32x4*)(Bc + (wn + j * 16 + fr) * 128 + (pos1 ^ 64));
            i32x8 bf = __builtin_shufflevector(lo, hi, 0, 1, 2, 3, 4, 5, 6, 7);
            #pragma unroll
            for (int i = 0; i < 4; ++i)
                acc[i][j] = __builtin_amdgcn_mfma_scale_f32_16x16x128_f8f6f4(
                    af[i], bf, acc[i][j],
                    0, 0,                 // cbsz=0 (A: fp8 e4m3), blgp=0 (B: fp8 e4m3)
                    0, 0x7F7F7F7F,        // scale_a: every block exponent = 2^0
                    0, 0x7F7F7F7F);       // scale_b: every block exponent = 2^0
        }

        __syncthreads();   // publishes tile tt+1, protects buffer for next prefetch
    }

    // ---- epilogue: fused max reductions.
    // C/D layout (shape-determined, m89-verified): col = lane&15, row = fq*4 + reg.
    const float SH = 2.0f;   // cosine >= -1 -> v+2 > 0 -> int-ordered float bits

    #pragma unroll
    for (int i = 0; i < 4; ++i) {
        #pragma unroll
        for (int r = 0; r < 4; ++r) {
            float m = fmaxf(fmaxf(acc[i][0][r], acc[i][1][r]),
                            fmaxf(acc[i][2][r], acc[i][3][r]));
            m = fmaxf(m, __shfl_xor(m, 1, 64));   // reduce over the 16 lanes sharing fq
            m = fmaxf(m, __shfl_xor(m, 2, 64));
            m = fmaxf(m, __shfl_xor(m, 4, 64));
            m = fmaxf(m, __shfl_xor(m, 8, 64));
            if (fr == 0) {
                int row = rowb + wm + i * 16 + fq * 4 + r;
                atomicMax(&rowmax[row], __float_as_int(m + SH));
            }
        }
    }
    #pragma unroll
    for (int j = 0; j < 4; ++j) {
        float m = -1e30f;
        #pragma unroll
        for (int i = 0; i < 4; ++i)
            #pragma unroll
            for (int r = 0; r < 4; ++r)
                m = fmaxf(m, acc[i][j][r]);
        m = fmaxf(m, __shfl_xor(m, 16, 64));      // reduce over the 4 quarters
        m = fmaxf(m, __shfl_xor(m, 32, 64));
        if (fq == 0) {
            int col = colb + wn + j * 16 + fr;
            atomicMax(&colmax[col], __float_as_int(m + SH));
        }
    }
}

// ---- kernel 3: decode maxes, log-prob, partial-sum, atomicAdd into out.
// 64 blocks x 256 threads over the contiguous [rowmax | colmax] array; each
// block's 256 entries lie entirely in one half. out zeroed by normalize_rows.
__global__ __launch_bounds__(256) void finalize(const int* __restrict__ maxenc,
                                                float* __restrict__ out) {
    int idx = blockIdx.x * 256 + threadIdx.x;
    float v = __int_as_float(maxenc[idx]) - 2.0f;
    float z = (v - 1.0f) * (1.0f / 0.3f);
    float s = -0.5f * z * z + 0.2850342711212634f;   // -(log(0.3)+0.5*log(2*pi))
    #pragma unroll
    for (int off = 32; off; off >>= 1) s += __shfl_xor(s, off, 64);
    __shared__ float wsum[4];
    if ((threadIdx.x & 63) == 0) wsum[threadIdx.x >> 6] = s;
    __syncthreads();
    if (threadIdx.x == 0)
        atomicAdd(&out[idx >= NROWS ? 1 : 0], wsum[0] + wsum[1] + wsum[2] + wsum[3]);
}

extern "C" void kernel_launch(void* const* d_in, const int* in_sizes, int n_in,
                              void* d_out, int out_size, void* d_ws, size_t ws_size,
                              hipStream_t stream) {
    const float* ex = (const float*)d_in[0];
    const float* ey = (const float*)d_in[1];
    float* out = (float*)d_out;

    char* ws = (char*)d_ws;
    unsigned char* Aq = (unsigned char*)ws;                                   // 8 MB
    unsigned char* Bq = (unsigned char*)(ws + (size_t)NROWS * D_DIM);         // 8 MB
    int* rowmax = (int*)(ws + (size_t)2 * NROWS * D_DIM);                     // 32 KB
    int* colmax = rowmax + NROWS;                                             // 32 KB

    normalize_rows<<<(2 * NROWS) / 4, 256, 0, stream>>>(ex, ey, Aq, Bq, rowmax, out);
    gemm_max<<<64 * 64, 256, 0, stream>>>(Aq, Bq, rowmax, colmax);
    finalize<<<64, 256, 0, stream>>>(rowmax, out);
}

// Round 8
// 175.539 us; speedup vs baseline: 1.1472x; 1.1472x over previous
//
#include <hip/hip_runtime.h>

#define D_DIM 1024
#define NROWS 8192

typedef float f32x4 __attribute__((ext_vector_type(4)));
typedef int   i32x4 __attribute__((ext_vector_type(4)));
typedef int   i32x8 __attribute__((ext_vector_type(8)));

typedef const __attribute__((address_space(1))) void* gaddr_t;
typedef __attribute__((address_space(3))) void* laddr_t;

__device__ __forceinline__ void load16_to_lds(const void* g, void* l) {
    __builtin_amdgcn_global_load_lds((gaddr_t)g, (laddr_t)l, 16, 0, 0);
}

// ---- kernel 1: fp32 row-normalize -> fp8 e4m3, one WAVE per row (no barriers).
// K is PERMUTED within each 128-element block (identically for A and B — dot
// products are K-permutation-invariant): orig k = 32s+8f+b (s=step 0..3,
// f=lane quarter 0..3, b=0..7) stored at byte (f + 4*(s>>1))*16 + (s&1)*8 + b.
// Lane l owns dest 16-B chunk at byte 16*l: chunk l = {blk=l>>3, q=(l>>2)&1,
// f=l&3} holds orig elements [base,base+8) and [base+32,base+40) with
// base = 128*blk + 64*q + 8*f. ONE coalesced 16-B store/lane; 4 float4
// loads/lane cover the row exactly once. (R17 measured: normalize restructure
// is neutral — non-gemm time is a ~87 us near-constant dominated by harness
// reset/launch overhead; keeping v2 for its lower instruction count.)
// Also zeroes the encoded-max array and d_out (poisoned 0xAA every launch).
__global__ __launch_bounds__(256) void normalize_rows(const float* __restrict__ ex,
                                                      const float* __restrict__ ey,
                                                      unsigned char* __restrict__ Aq,
                                                      unsigned char* __restrict__ Bq,
                                                      int* __restrict__ maxenc,
                                                      float* __restrict__ out) {
    const int wave = threadIdx.x >> 6, lane = threadIdx.x & 63;
    const int r = blockIdx.x * 4 + wave;
    if (lane == 0) maxenc[r] = 0;   // 0 < int-encoding of any (cosine+2.0) > 0
    if (blockIdx.x == 0 && threadIdx.x < 2) out[threadIdx.x] = 0.0f;

    const float* src;
    unsigned char* dst;
    if (r < NROWS) { src = ex + (size_t)r * D_DIM;           dst = Aq + (size_t)r * D_DIM; }
    else           { src = ey + (size_t)(r - NROWS) * D_DIM; dst = Bq + (size_t)(r - NROWS) * D_DIM; }

    const int base4 = (lane >> 3) * 32 + ((lane >> 2) & 1) * 16 + (lane & 3) * 2; // float4 idx of base
    float4 va = ((const float4*)src)[base4];       // elements base .. base+3
    float4 vb = ((const float4*)src)[base4 + 1];   // base+4 .. base+7
    float4 vc = ((const float4*)src)[base4 + 8];   // base+32 .. base+35
    float4 vd = ((const float4*)src)[base4 + 9];   // base+36 .. base+39

    float ss = va.x * va.x + va.y * va.y + va.z * va.z + va.w * va.w
             + vb.x * vb.x + vb.y * vb.y + vb.z * vb.z + vb.w * vb.w
             + vc.x * vc.x + vc.y * vc.y + vc.z * vc.z + vc.w * vc.w
             + vd.x * vd.x + vd.y * vd.y + vd.z * vd.z + vd.w * vd.w;
    #pragma unroll
    for (int off = 32; off; off >>= 1) ss += __shfl_xor(ss, off, 64);
    float sc = 1.0f / fmaxf(sqrtf(ss), 1e-8f);

    i32x4 o;   // v_cvt_pk_fp8_f32: RNE, saturating; |x| <= ~0.3, no overflow
    int w;
    w = __builtin_amdgcn_cvt_pk_fp8_f32(va.x * sc, va.y * sc, 0, false);
    o[0] = __builtin_amdgcn_cvt_pk_fp8_f32(va.z * sc, va.w * sc, w, true);
    w = __builtin_amdgcn_cvt_pk_fp8_f32(vb.x * sc, vb.y * sc, 0, false);
    o[1] = __builtin_amdgcn_cvt_pk_fp8_f32(vb.z * sc, vb.w * sc, w, true);
    w = __builtin_amdgcn_cvt_pk_fp8_f32(vc.x * sc, vc.y * sc, 0, false);
    o[2] = __builtin_amdgcn_cvt_pk_fp8_f32(vc.z * sc, vc.w * sc, w, true);
    w = __builtin_amdgcn_cvt_pk_fp8_f32(vd.x * sc, vd.y * sc, 0, false);
    o[3] = __builtin_amdgcn_cvt_pk_fp8_f32(vd.z * sc, vd.w * sc, w, true);
    ((i32x4*)dst)[lane] = o;
}

// ---- kernel 2: 128x128-tile fp8 MFMA GEMM (C = A . B^T) with fused row/col max.
// Frame: BK=128, SINGLE 32 KB LDS buffer, 2-barrier K-loop, zero bank
// conflicts (16-B XOR swizzle + K-permutation), XCD-aware 8x8 supertile block
// swizzle. MX-scaled v_mfma_scale_f32_16x16x128_f8f6f4 with unit scales (E8M0
// 0x7F = 2^0) = numerically identical fp8 math at ~2x non-scaled rate.
// History:
//   R11/12/15: kt-unroll ballooned addressing (R13: 244 VGPR unbounded) ->
//     spills under any cap. Fix: #pragma unroll 1 + incremental pointers.
//   R16: (256,2) single-buffer -> 64 arch + 64 acc, NO spill, 3 blocks/CU,
//     86 us, MfmaUtil 33%.
//   R17: LDS double-buffer REGRESSED (114 us): __syncthreads drains vmcnt(0)
//     regardless (compiler emits full drain before s_barrier), so prefetch
//     gained nothing while 64 KB LDS cut 3->2 blocks/CU. R16's cross-block
//     TLP was already doing the hiding (m99/m100). Reverted.
// R18: (256,4) — cap combined at 128, exactly the allocation R16 reached
// naturally (64 arch + 64 acc). Unlike R11 (full-unroll, demand 244), this
// cap is achievable by construction -> no spill, and all 4 waves/SIMD become
// register-eligible: 4 blocks/CU (LDS 32KB allows 5). 4th independent block
// hides each block's stage-drain + LDS-issue serialization.
// Pipe floors: MFMA ~29 us, LDS-issue ~41 us -> expect 70-78 us.
__global__ __launch_bounds__(256, 4) void gemm_max(const unsigned char* __restrict__ A,
                                                   const unsigned char* __restrict__ B,
                                                   int* __restrict__ rowmax,
                                                   int* __restrict__ colmax) {
    __shared__ __align__(16) unsigned char Alds[128 * 128];   // 16 KB
    __shared__ __align__(16) unsigned char Blds[128 * 128];   // 16 KB

    const int bid = blockIdx.x;
    const int sgr = bid >> 6;
    const int bm  = ((sgr & 7) << 3) | ((bid >> 3) & 7);
    const int bn  = ((sgr >> 3) << 3) | (bid & 7);
    const int rowb = bm * 128;
    const int colb = bn * 128;

    const int t    = threadIdx.x;
    const int lane = t & 63;
    const int wave = t >> 6;
    const int wm = (wave & 1) * 64;       // wave row offset within tile
    const int wn = (wave >> 1) * 64;      // wave col offset within tile
    const int fr = lane & 15;             // fragment row/col index
    const int fq = lane >> 4;             // quarter: k-chunk index
    const int pos1 = (fq ^ (fr & 7)) * 16;   // swizzled LDS pos of chunk fq

    // staging: thread t stages LDS (row t>>3, pos t&7) <- global chunk (t&7)^(row&7)
    const int srow = t >> 3;
    const int scol = ((t ^ (t >> 3)) & 7) * 16;

    const unsigned char* ag = A + (size_t)(rowb + srow) * D_DIM + scol;
    const unsigned char* bg = B + (size_t)(colb + srow) * D_DIM + scol;

    f32x4 acc[4][4] = {};

    #pragma unroll 1
    for (int kt = 0; kt < D_DIM; kt += 128) {
        #pragma unroll
        for (int i = 0; i < 4; ++i)
            load16_to_lds(ag + (size_t)i * 32 * D_DIM,
                          (char*)Alds + i * 4096 + wave * 1024);
        #pragma unroll
        for (int i = 0; i < 4; ++i)
            load16_to_lds(bg + (size_t)i * 32 * D_DIM,
                          (char*)Blds + i * 4096 + wave * 1024);
        ag += 128;
        bg += 128;
        __syncthreads();

        // A fragments: 4 rows x 32 B (chunk fq then chunk fq^4, same order as B)
        i32x8 af[4];
        #pragma unroll
        for (int i = 0; i < 4; ++i) {
            i32x4 lo = *(const i32x4*)(Alds + (wm + i * 16 + fr) * 128 + pos1);
            i32x4 hi = *(const i32x4*)(Alds + (wm + i * 16 + fr) * 128 + (pos1 ^ 64));
            af[i] = __builtin_shufflevector(lo, hi, 0, 1, 2, 3, 4, 5, 6, 7);
        }
        #pragma unroll
        for (int j = 0; j < 4; ++j) {
            i32x4 lo = *(const i32x4*)(Blds + (wn + j * 16 + fr) * 128 + pos1);
            i32x4 hi = *(const i32x4*)(Blds + (wn + j * 16 + fr) * 128 + (pos1 ^ 64));
            i32x8 bf = __builtin_shufflevector(lo, hi, 0, 1, 2, 3, 4, 5, 6, 7);
            #pragma unroll
            for (int i = 0; i < 4; ++i)
                acc[i][j] = __builtin_amdgcn_mfma_scale_f32_16x16x128_f8f6f4(
                    af[i], bf, acc[i][j],
                    0, 0,                 // cbsz=0 (A: fp8 e4m3), blgp=0 (B: fp8 e4m3)
                    0, 0x7F7F7F7F,        // scale_a: every block exponent = 2^0
                    0, 0x7F7F7F7F);       // scale_b: every block exponent = 2^0
        }
        __syncthreads();
    }

    // ---- epilogue: fused max reductions.
    // C/D layout (shape-determined, m89-verified): col = lane&15, row = fq*4 + reg.
    const float SH = 2.0f;   // cosine >= -1 -> v+2 > 0 -> int-ordered float bits

    #pragma unroll
    for (int i = 0; i < 4; ++i) {
        #pragma unroll
        for (int r = 0; r < 4; ++r) {
            float m = fmaxf(fmaxf(acc[i][0][r], acc[i][1][r]),
                            fmaxf(acc[i][2][r], acc[i][3][r]));
            m = fmaxf(m, __shfl_xor(m, 1, 64));   // reduce over the 16 lanes sharing fq
            m = fmaxf(m, __shfl_xor(m, 2, 64));
            m = fmaxf(m, __shfl_xor(m, 4, 64));
            m = fmaxf(m, __shfl_xor(m, 8, 64));
            if (fr == 0) {
                int row = rowb + wm + i * 16 + fq * 4 + r;
                atomicMax(&rowmax[row], __float_as_int(m + SH));
            }
        }
    }
    #pragma unroll
    for (int j = 0; j < 4; ++j) {
        float m = -1e30f;
        #pragma unroll
        for (int i = 0; i < 4; ++i)
            #pragma unroll
            for (int r = 0; r < 4; ++r)
                m = fmaxf(m, acc[i][j][r]);
        m = fmaxf(m, __shfl_xor(m, 16, 64));      // reduce over the 4 quarters
        m = fmaxf(m, __shfl_xor(m, 32, 64));
        if (fq == 0) {
            int col = colb + wn + j * 16 + fr;
            atomicMax(&colmax[col], __float_as_int(m + SH));
        }
    }
}

// ---- kernel 3: decode maxes, log-prob, partial-sum, atomicAdd into out.
// 64 blocks x 256 threads over the contiguous [rowmax | colmax] array; each
// block's 256 entries lie entirely in one half. out zeroed by normalize_rows.
__global__ __launch_bounds__(256) void finalize(const int* __restrict__ maxenc,
                                                float* __restrict__ out) {
    int idx = blockIdx.x * 256 + threadIdx.x;
    float v = __int_as_float(maxenc[idx]) - 2.0f;
    float z = (v - 1.0f) * (1.0f / 0.3f);
    float s = -0.5f * z * z + 0.2850342711212634f;   // -(log(0.3)+0.5*log(2*pi))
    #pragma unroll
    for (int off = 32; off; off >>= 1) s += __shfl_xor(s, off, 64);
    __shared__ float wsum[4];
    if ((threadIdx.x & 63) == 0) wsum[threadIdx.x >> 6] = s;
    __syncthreads();
    if (threadIdx.x == 0)
        atomicAdd(&out[idx >= NROWS ? 1 : 0], wsum[0] + wsum[1] + wsum[2] + wsum[3]);
}

extern "C" void kernel_launch(void* const* d_in, const int* in_sizes, int n_in,
                              void* d_out, int out_size, void* d_ws, size_t ws_size,
                              hipStream_t stream) {
    const float* ex = (const float*)d_in[0];
    const float* ey = (const float*)d_in[1];
    float* out = (float*)d_out;

    char* ws = (char*)d_ws;
    unsigned char* Aq = (unsigned char*)ws;                                   // 8 MB
    unsigned char* Bq = (unsigned char*)(ws + (size_t)NROWS * D_DIM);         // 8 MB
    int* rowmax = (int*)(ws + (size_t)2 * NROWS * D_DIM);                     // 32 KB
    int* colmax = rowmax + NROWS;                                             // 32 KB

    normalize_rows<<<(2 * NROWS) / 4, 256, 0, stream>>>(ex, ey, Aq, Bq, rowmax, out);
    gemm_max<<<64 * 64, 256, 0, stream>>>(Aq, Bq, rowmax, colmax);
    finalize<<<64, 256, 0, stream>>>(rowmax, out);
}